// Round 1
// baseline (600.788 us; speedup 1.0000x reference)
//
#include <hip/hip_runtime.h>

typedef __attribute__((ext_vector_type(8))) short bf16x8;
typedef __attribute__((ext_vector_type(4))) float f32x4;
typedef unsigned short u16;
typedef unsigned int u32;

__device__ __forceinline__ u16 f2b(float f) {
  u32 u = __float_as_uint(f);
  u = (u + 0x7fffu + ((u >> 16) & 1u)) >> 16;
  return (u16)u;
}
__device__ __forceinline__ float b2f(u16 b) {
  return __uint_as_float(((u32)b) << 16);
}

// ---------------- convert fp32 -> bf16 (vectorized) ----------------
__global__ __launch_bounds__(256) void cvt_bf16(const float* __restrict__ in,
                                                u16* __restrict__ out, int n4) {
  int i = blockIdx.x * 256 + threadIdx.x;
  if (i >= n4) return;
  float4 v = ((const float4*)in)[i];
  ushort4 o;
  o.x = f2b(v.x); o.y = f2b(v.y); o.z = f2b(v.z); o.w = f2b(v.w);
  ((ushort4*)out)[i] = o;
}

// ------------- transpose weight [R][C] fp32 -> [C][R] bf16 -------------
__global__ __launch_bounds__(256) void transpose_w(const float* __restrict__ in,
                                                   u16* __restrict__ out,
                                                   int R, int C) {
  __shared__ float t[32][33];
  int tid = threadIdx.x, tx = tid & 31, ty = tid >> 5;
  int rb = blockIdx.y * 32, cb = blockIdx.x * 32;
  for (int i = 0; i < 4; i++)
    t[ty + i * 8][tx] = in[(size_t)(rb + ty + i * 8) * C + cb + tx];
  __syncthreads();
  for (int i = 0; i < 4; i++)
    out[(size_t)(cb + ty + i * 8) * R + rb + tx] = f2b(t[tx][ty + i * 8]);
}

// ------------- transpose V [bh][2048][64] -> Vt [bh][64][2048] (bf16) -------------
__global__ __launch_bounds__(256) void transpose_v(const u16* __restrict__ V,
                                                   u16* __restrict__ Vt) {
  __shared__ u16 t[64][72];
  const int tid = threadIdx.x;
  const size_t base = (size_t)blockIdx.y * (2048 * 64);
  const int s0 = blockIdx.x * 64;
  const int rr = tid >> 3, cb = (tid & 7) * 8;
  for (int i = 0; i < 2; i++) {
    int r = rr + i * 32;
    uint4 v = *(const uint4*)(V + base + (size_t)(s0 + r) * 64 + cb);
    *(uint4*)&t[r][cb] = v;
  }
  __syncthreads();
  for (int i = 0; i < 2; i++) {
    int d = rr + i * 32;
    u16 tmp[8];
    for (int j = 0; j < 8; j++) tmp[j] = t[cb + j][d];
    *(uint4*)(Vt + base + (size_t)d * 2048 + s0 + cb) = *(uint4*)tmp;
  }
}

// ---------------- GEMM: C[M,N] = A[M,K](bf16) * Bt[N,K]^T + bias ----------------
// MODE 0: fp32 out; 1: bf16 out; 2: bf16 relu out; 3: bf16 out in [B,H,S,64] layout
template <int MODE>
__global__ __launch_bounds__(256) void gemm_bt(const u16* __restrict__ A,
                                               const u16* __restrict__ Bt,
                                               const float* __restrict__ bias,
                                               void* __restrict__ out,
                                               int M, int N, int K) {
  __shared__ u16 sA[128][40];
  __shared__ u16 sB[128][40];
  const int tid = threadIdx.x, lane = tid & 63, wid = tid >> 6;
  const int l16 = lane & 15, lq = lane >> 4;
  const int wr = wid >> 1, wc = wid & 1;
  const int bm = blockIdx.x, bn = blockIdx.y;
  const size_t abase = (size_t)bm * 128 * K;
  const size_t bbase = (size_t)bn * 128 * K;
  const int r0 = tid >> 2, cb0 = (tid & 3) * 8;

  f32x4 zero4 = {0.f, 0.f, 0.f, 0.f};
  f32x4 acc[4][4];
  for (int i = 0; i < 4; i++)
    for (int j = 0; j < 4; j++) acc[i][j] = zero4;

  for (int kk = 0; kk < K; kk += 32) {
    uint4 a0 = *(const uint4*)(A + abase + (size_t)r0 * K + kk + cb0);
    uint4 a1 = *(const uint4*)(A + abase + (size_t)(r0 + 64) * K + kk + cb0);
    uint4 b0 = *(const uint4*)(Bt + bbase + (size_t)r0 * K + kk + cb0);
    uint4 b1 = *(const uint4*)(Bt + bbase + (size_t)(r0 + 64) * K + kk + cb0);
    __syncthreads();
    *(uint4*)&sA[r0][cb0] = a0;
    *(uint4*)&sA[r0 + 64][cb0] = a1;
    *(uint4*)&sB[r0][cb0] = b0;
    *(uint4*)&sB[r0 + 64][cb0] = b1;
    __syncthreads();
    bf16x8 af[4], bfr[4];
    for (int i = 0; i < 4; i++)
      af[i] = *(const bf16x8*)&sA[wr * 64 + i * 16 + l16][lq * 8];
    for (int j = 0; j < 4; j++)
      bfr[j] = *(const bf16x8*)&sB[wc * 64 + j * 16 + l16][lq * 8];
    for (int i = 0; i < 4; i++)
      for (int j = 0; j < 4; j++)
        acc[i][j] = __builtin_amdgcn_mfma_f32_16x16x32_bf16(af[i], bfr[j],
                                                            acc[i][j], 0, 0, 0);
  }

  for (int i = 0; i < 4; i++) {
    int gm0 = bm * 128 + wr * 64 + i * 16 + lq * 4;
    for (int j = 0; j < 4; j++) {
      int gn = bn * 128 + wc * 64 + j * 16 + l16;
      float bv = bias[gn];
      for (int r = 0; r < 4; r++) {
        float v = acc[i][j][r] + bv;
        int gm = gm0 + r;
        if constexpr (MODE == 0) {
          ((float*)out)[(size_t)gm * N + gn] = v;
        } else if constexpr (MODE == 1) {
          ((u16*)out)[(size_t)gm * N + gn] = f2b(v);
        } else if constexpr (MODE == 2) {
          ((u16*)out)[(size_t)gm * N + gn] = f2b(v > 0.f ? v : 0.f);
        } else {
          int b = gm >> 11, s = gm & 2047, h = gn >> 6, d = gn & 63;
          ((u16*)out)[((size_t)(b * 16 + h) * 2048 + s) * 64 + d] = f2b(v);
        }
      }
    }
  }
}

// ---------------- flash attention fwd ----------------
// Q,K: [BH][2048][64] bf16; Vt: [BH][64][2048] bf16; ctx: [B,S,1024] bf16
__global__ __launch_bounds__(256) void attn_fwd(const u16* __restrict__ Q,
                                                const u16* __restrict__ Kb,
                                                const u16* __restrict__ Vt,
                                                u16* __restrict__ ctx) {
  __shared__ u16 sK[64][72];
  __shared__ u16 sV[64][72];   // [d][kv]
  __shared__ u16 sP[4][16][72];
  const int tid = threadIdx.x, lane = tid & 63, wid = tid >> 6;
  const int l16 = lane & 15, lq = lane >> 4;
  const int bh = blockIdx.y, qt = blockIdx.x;
  const size_t base = (size_t)bh * (2048 * 64);

  bf16x8 qf[2];
  {
    int qrow = qt * 64 + wid * 16 + l16;
    qf[0] = *(const bf16x8*)(Q + base + (size_t)qrow * 64 + lq * 8);
    qf[1] = *(const bf16x8*)(Q + base + (size_t)qrow * 64 + 32 + lq * 8);
  }
  f32x4 zero4 = {0.f, 0.f, 0.f, 0.f};
  f32x4 o[4];
  for (int j = 0; j < 4; j++) o[j] = zero4;
  float mrow[4] = {-3e38f, -3e38f, -3e38f, -3e38f};
  float lrow[4] = {0.f, 0.f, 0.f, 0.f};
  const int sr = tid >> 3, scb = (tid & 7) * 8;

  for (int kv0 = 0; kv0 < 2048; kv0 += 64) {
    uint4 k0 = *(const uint4*)(Kb + base + (size_t)(kv0 + sr) * 64 + scb);
    uint4 k1 = *(const uint4*)(Kb + base + (size_t)(kv0 + sr + 32) * 64 + scb);
    uint4 v0 = *(const uint4*)(Vt + base + (size_t)sr * 2048 + kv0 + scb);
    uint4 v1 = *(const uint4*)(Vt + base + (size_t)(sr + 32) * 2048 + kv0 + scb);
    __syncthreads();
    *(uint4*)&sK[sr][scb] = k0;
    *(uint4*)&sK[sr + 32][scb] = k1;
    *(uint4*)&sV[sr][scb] = v0;
    *(uint4*)&sV[sr + 32][scb] = v1;
    __syncthreads();

    f32x4 sf[4];
    for (int j = 0; j < 4; j++) sf[j] = zero4;
    for (int ks = 0; ks < 2; ks++)
      for (int j = 0; j < 4; j++) {
        bf16x8 kf = *(const bf16x8*)&sK[j * 16 + l16][ks * 32 + lq * 8];
        sf[j] = __builtin_amdgcn_mfma_f32_16x16x32_bf16(qf[ks], kf, sf[j], 0, 0, 0);
      }

    float osc[4];
    for (int r = 0; r < 4; r++) {
      float v = fmaxf(fmaxf(sf[0][r], sf[1][r]), fmaxf(sf[2][r], sf[3][r])) * 0.125f;
      for (int off = 1; off < 16; off <<= 1) v = fmaxf(v, __shfl_xor(v, off));
      float mn = fmaxf(mrow[r], v);
      osc[r] = __expf(mrow[r] - mn);
      mrow[r] = mn;
      lrow[r] *= osc[r];
    }
    float rs[4] = {0.f, 0.f, 0.f, 0.f};
    for (int j = 0; j < 4; j++)
      for (int r = 0; r < 4; r++) {
        float p = __expf(sf[j][r] * 0.125f - mrow[r]);
        sf[j][r] = p;
        rs[r] += p;
      }
    for (int r = 0; r < 4; r++) {
      float v = rs[r];
      for (int off = 1; off < 16; off <<= 1) v += __shfl_xor(v, off);
      lrow[r] += v;
      for (int j = 0; j < 4; j++) o[j][r] *= osc[r];
    }
    for (int j = 0; j < 4; j++)
      for (int r = 0; r < 4; r++)
        sP[wid][lq * 4 + r][j * 16 + l16] = f2b(sf[j][r]);
    __syncthreads();
    for (int ks = 0; ks < 2; ks++) {
      bf16x8 pf = *(const bf16x8*)&sP[wid][l16][ks * 32 + lq * 8];
      for (int j = 0; j < 4; j++) {
        bf16x8 vf = *(const bf16x8*)&sV[j * 16 + l16][ks * 32 + lq * 8];
        o[j] = __builtin_amdgcn_mfma_f32_16x16x32_bf16(pf, vf, o[j], 0, 0, 0);
      }
    }
  }

  const int b = bh >> 4, h = bh & 15;
  for (int j = 0; j < 4; j++)
    for (int r = 0; r < 4; r++) {
      int srow = qt * 64 + wid * 16 + lq * 4 + r;
      int d = j * 16 + l16;
      float v = o[j][r] / lrow[r];
      ctx[((size_t)(b * 2048 + srow)) * 1024 + h * 64 + d] = f2b(v);
    }
}

// ---------------- residual + LayerNorm ----------------
// y = LN(a + b) * g + be ; writes fp32 out, optional bf16 out
template <int B_BF16, int WRITE_BF16>
__global__ __launch_bounds__(256) void ln_res(const float* __restrict__ a,
                                              const void* __restrict__ bsrc,
                                              const float* __restrict__ g,
                                              const float* __restrict__ be,
                                              float* __restrict__ outf,
                                              u16* __restrict__ outb) {
  const int row = blockIdx.x, tid = threadIdx.x;
  const size_t off = (size_t)row * 1024 + tid * 4;
  float4 x = *(const float4*)(a + off);
  if constexpr (B_BF16) {
    const u16* bp = (const u16*)bsrc + off;
    x.x += b2f(bp[0]); x.y += b2f(bp[1]); x.z += b2f(bp[2]); x.w += b2f(bp[3]);
  } else {
    float4 bb = *(const float4*)((const float*)bsrc + off);
    x.x += bb.x; x.y += bb.y; x.z += bb.z; x.w += bb.w;
  }
  float s = x.x + x.y + x.z + x.w;
  float s2 = x.x * x.x + x.y * x.y + x.z * x.z + x.w * x.w;
  for (int o = 1; o < 64; o <<= 1) {
    s += __shfl_xor(s, o);
    s2 += __shfl_xor(s2, o);
  }
  __shared__ float rbuf[8];
  int lane = tid & 63, wid = tid >> 6;
  if (lane == 0) { rbuf[wid] = s; rbuf[4 + wid] = s2; }
  __syncthreads();
  s = rbuf[0] + rbuf[1] + rbuf[2] + rbuf[3];
  s2 = rbuf[4] + rbuf[5] + rbuf[6] + rbuf[7];
  float mu = s * (1.f / 1024.f);
  float var = s2 * (1.f / 1024.f) - mu * mu;
  float rstd = rsqrtf(var + 1e-5f);
  int c = tid * 4;
  float y0 = (x.x - mu) * rstd * g[c + 0] + be[c + 0];
  float y1 = (x.y - mu) * rstd * g[c + 1] + be[c + 1];
  float y2 = (x.z - mu) * rstd * g[c + 2] + be[c + 2];
  float y3 = (x.w - mu) * rstd * g[c + 3] + be[c + 3];
  float4 y; y.x = y0; y.y = y1; y.z = y2; y.w = y3;
  *(float4*)(outf + off) = y;
  if constexpr (WRITE_BF16) {
    ushort4 yb;
    yb.x = f2b(y0); yb.y = f2b(y1); yb.z = f2b(y2); yb.w = f2b(y3);
    *(ushort4*)(outb + off) = yb;
  }
}

// ---------------- launch ----------------
extern "C" void kernel_launch(void* const* d_in, const int* in_sizes, int n_in,
                              void* d_out, int out_size, void* d_ws, size_t ws_size,
                              hipStream_t stream) {
  const float* src = (const float*)d_in[0];
  const float* Wq = (const float*)d_in[1];
  const float* bq = (const float*)d_in[2];
  const float* Wk = (const float*)d_in[3];
  const float* bk = (const float*)d_in[4];
  const float* Wv = (const float*)d_in[5];
  const float* bv = (const float*)d_in[6];
  const float* Wo = (const float*)d_in[7];
  const float* bo = (const float*)d_in[8];
  const float* W1 = (const float*)d_in[9];
  const float* b1 = (const float*)d_in[10];
  const float* W2 = (const float*)d_in[11];
  const float* b2 = (const float*)d_in[12];
  const float* g1 = (const float*)d_in[13];
  const float* be1 = (const float*)d_in[14];
  const float* g2 = (const float*)d_in[15];
  const float* be2 = (const float*)d_in[16];
  float* out = (float*)d_out;
  char* ws = (char*)d_ws;
  const size_t MB = 1ull << 20;

  u16* XB   = (u16*)(ws + 0);        // 16MB, later CTX, later FF
  u16* WQT  = (u16*)(ws + 16 * MB);  // 2MB
  u16* WKT  = (u16*)(ws + 18 * MB);
  u16* WVT  = (u16*)(ws + 20 * MB);
  u16* WOT  = (u16*)(ws + 22 * MB);
  u16* W1T  = (u16*)(ws + 24 * MB);  // 8MB
  u16* W2T  = (u16*)(ws + 32 * MB);  // 8MB
  u16* Qb   = (u16*)(ws + 40 * MB);  // 16MB
  u16* Kbuf = (u16*)(ws + 56 * MB);  // 16MB
  u16* Vtmp = (u16*)(ws + 72 * MB);  // 16MB
  u16* Vt   = (u16*)(ws + 88 * MB);  // 16MB
  u16* CTX  = (u16*)(ws + 0);        // reuse XB
  float* AO = (float*)(ws + 40 * MB);   // 32MB, reuse Q/K
  float* XF = (float*)(ws + 104 * MB);  // 32MB
  u16* XBUF = (u16*)(ws + 136 * MB);    // 16MB  (peak 152MB)
  u16* H1   = (u16*)(ws + 40 * MB);     // 64MB, reuse [40,104)
  u16* FF   = (u16*)(ws + 0);           // 16MB, reuse CTX

  cvt_bf16<<<dim3(8192), dim3(256), 0, stream>>>(src, XB, 2097152);
  transpose_w<<<dim3(32, 32), dim3(256), 0, stream>>>(Wq, WQT, 1024, 1024);
  transpose_w<<<dim3(32, 32), dim3(256), 0, stream>>>(Wk, WKT, 1024, 1024);
  transpose_w<<<dim3(32, 32), dim3(256), 0, stream>>>(Wv, WVT, 1024, 1024);
  transpose_w<<<dim3(32, 32), dim3(256), 0, stream>>>(Wo, WOT, 1024, 1024);
  transpose_w<<<dim3(128, 32), dim3(256), 0, stream>>>(W1, W1T, 1024, 4096);
  transpose_w<<<dim3(32, 128), dim3(256), 0, stream>>>(W2, W2T, 4096, 1024);

  gemm_bt<3><<<dim3(64, 8), dim3(256), 0, stream>>>(XB, WQT, bq, Qb, 8192, 1024, 1024);
  gemm_bt<3><<<dim3(64, 8), dim3(256), 0, stream>>>(XB, WKT, bk, Kbuf, 8192, 1024, 1024);
  gemm_bt<3><<<dim3(64, 8), dim3(256), 0, stream>>>(XB, WVT, bv, Vtmp, 8192, 1024, 1024);
  transpose_v<<<dim3(32, 64), dim3(256), 0, stream>>>(Vtmp, Vt);
  attn_fwd<<<dim3(32, 64), dim3(256), 0, stream>>>(Qb, Kbuf, Vt, CTX);
  gemm_bt<0><<<dim3(64, 8), dim3(256), 0, stream>>>(CTX, WOT, bo, AO, 8192, 1024, 1024);
  ln_res<0, 1><<<dim3(8192), dim3(256), 0, stream>>>(src, AO, g1, be1, XF, XBUF);
  gemm_bt<2><<<dim3(64, 32), dim3(256), 0, stream>>>(XBUF, W1T, b1, H1, 8192, 4096, 1024);
  gemm_bt<1><<<dim3(64, 8), dim3(256), 0, stream>>>(H1, W2T, b2, FF, 8192, 1024, 4096);
  ln_res<1, 0><<<dim3(8192), dim3(256), 0, stream>>>(XF, FF, g2, be2, out, nullptr);
}

// Round 2
// 515.725 us; speedup vs baseline: 1.1649x; 1.1649x over previous
//
#include <hip/hip_runtime.h>

typedef __attribute__((ext_vector_type(8))) short bf16x8;
typedef __attribute__((ext_vector_type(4))) float f32x4;
typedef unsigned short u16;
typedef unsigned int u32;

__device__ __forceinline__ u16 f2b(float f) {
  u32 u = __float_as_uint(f);
  u = (u + 0x7fffu + ((u >> 16) & 1u)) >> 16;
  return (u16)u;
}
__device__ __forceinline__ float b2f(u16 b) {
  return __uint_as_float(((u32)b) << 16);
}

__device__ __forceinline__ void gload_lds16(const u16* g, u16* l) {
  __builtin_amdgcn_global_load_lds(
      (const __attribute__((address_space(1))) void*)g,
      (__attribute__((address_space(3))) void*)l, 16, 0, 0);
}

// ---------------- convert fp32 -> bf16 (vectorized) ----------------
__global__ __launch_bounds__(256) void cvt_bf16(const float* __restrict__ in,
                                                u16* __restrict__ out, int n4) {
  int i = blockIdx.x * 256 + threadIdx.x;
  if (i >= n4) return;
  float4 v = ((const float4*)in)[i];
  ushort4 o;
  o.x = f2b(v.x); o.y = f2b(v.y); o.z = f2b(v.z); o.w = f2b(v.w);
  ((ushort4*)out)[i] = o;
}

// ------------- transpose weight [R][C] fp32 -> [C][R] bf16 -------------
__global__ __launch_bounds__(256) void transpose_w(const float* __restrict__ in,
                                                   u16* __restrict__ out,
                                                   int R, int C) {
  __shared__ float t[32][33];
  int tid = threadIdx.x, tx = tid & 31, ty = tid >> 5;
  int rb = blockIdx.y * 32, cb = blockIdx.x * 32;
  for (int i = 0; i < 4; i++)
    t[ty + i * 8][tx] = in[(size_t)(rb + ty + i * 8) * C + cb + tx];
  __syncthreads();
  for (int i = 0; i < 4; i++)
    out[(size_t)(cb + ty + i * 8) * R + rb + tx] = f2b(t[tx][ty + i * 8]);
}

// ------------- transpose V [bh][2048][64] -> Vt [bh][64][2048] (bf16) -------------
__global__ __launch_bounds__(256) void transpose_v(const u16* __restrict__ V,
                                                   u16* __restrict__ Vt) {
  __shared__ u16 t[64][72];
  const int tid = threadIdx.x;
  const size_t base = (size_t)blockIdx.y * (2048 * 64);
  const int s0 = blockIdx.x * 64;
  const int rr = tid >> 3, cb = (tid & 7) * 8;
  for (int i = 0; i < 2; i++) {
    int r = rr + i * 32;
    uint4 v = *(const uint4*)(V + base + (size_t)(s0 + r) * 64 + cb);
    *(uint4*)&t[r][cb] = v;
  }
  __syncthreads();
  for (int i = 0; i < 2; i++) {
    int d = rr + i * 32;
    u16 tmp[8];
    for (int j = 0; j < 8; j++) tmp[j] = t[cb + j][d];
    *(uint4*)(Vt + base + (size_t)d * 2048 + s0 + cb) = *(uint4*)tmp;
  }
}

// ---------------- GEMM: C[M,N] = A[M,K](bf16) * Bt[N,K]^T + bias ----------------
// m97 structure: global_load_lds(16B) into linear LDS, 2 barriers/K-step.
// MODE 0: fp32 out; 1: bf16 out; 2: bf16 relu out; 3: bf16 out in [B,H,S,64] layout
template <int MODE>
__global__ __launch_bounds__(256) void gemm_bt(const u16* __restrict__ A,
                                               const u16* __restrict__ Bt,
                                               const float* __restrict__ bias,
                                               void* __restrict__ out,
                                               int M, int N, int K) {
  __shared__ u16 sA[128][32];
  __shared__ u16 sB[128][32];
  const int tid = threadIdx.x, lane = tid & 63, wid = tid >> 6;
  const int l16 = lane & 15, lq = lane >> 4;
  const int wr = wid >> 1, wc = wid & 1;
  const size_t abase = (size_t)blockIdx.x * 128 * K;
  const size_t bbase = (size_t)blockIdx.y * 128 * K;
  // staging: wave wid covers rows [wid*32, wid*32+32); each call = 16 rows (1KB)
  const int srow0 = wid * 32 + (lane >> 2);  // + 0 / +16 for the two calls
  const int scol = (lane & 3) * 8;           // u16 units (16B chunks)

  f32x4 acc[4][4];
  for (int i = 0; i < 4; i++)
    for (int j = 0; j < 4; j++) acc[i][j] = (f32x4){0.f, 0.f, 0.f, 0.f};

  for (int kk = 0; kk < K; kk += 32) {
    const u16* ap = A + abase + (size_t)srow0 * K + kk + scol;
    const u16* bp = Bt + bbase + (size_t)srow0 * K + kk + scol;
    __syncthreads();
    gload_lds16(ap, &sA[wid * 32][0]);
    gload_lds16(ap + (size_t)16 * K, &sA[wid * 32 + 16][0]);
    gload_lds16(bp, &sB[wid * 32][0]);
    gload_lds16(bp + (size_t)16 * K, &sB[wid * 32 + 16][0]);
    __syncthreads();
    bf16x8 af[4], bfr[4];
    for (int i = 0; i < 4; i++)
      af[i] = *(const bf16x8*)&sA[wr * 64 + i * 16 + l16][lq * 8];
    for (int j = 0; j < 4; j++)
      bfr[j] = *(const bf16x8*)&sB[wc * 64 + j * 16 + l16][lq * 8];
    for (int i = 0; i < 4; i++)
      for (int j = 0; j < 4; j++)
        acc[i][j] = __builtin_amdgcn_mfma_f32_16x16x32_bf16(af[i], bfr[j],
                                                            acc[i][j], 0, 0, 0);
  }

  for (int i = 0; i < 4; i++) {
    int gm0 = blockIdx.x * 128 + wr * 64 + i * 16 + lq * 4;
    for (int j = 0; j < 4; j++) {
      int gn = blockIdx.y * 128 + wc * 64 + j * 16 + l16;
      float bv = bias[gn];
      for (int r = 0; r < 4; r++) {
        float v = acc[i][j][r] + bv;
        int gm = gm0 + r;
        if constexpr (MODE == 0) {
          ((float*)out)[(size_t)gm * N + gn] = v;
        } else if constexpr (MODE == 1) {
          ((u16*)out)[(size_t)gm * N + gn] = f2b(v);
        } else if constexpr (MODE == 2) {
          ((u16*)out)[(size_t)gm * N + gn] = f2b(v > 0.f ? v : 0.f);
        } else {
          int b = gm >> 11, s = gm & 2047, h = gn >> 6, d = gn & 63;
          ((u16*)out)[((size_t)(b * 16 + h) * 2048 + s) * 64 + d] = f2b(v);
        }
      }
    }
  }
}

// ---------------- flash attention fwd (swapped QK^T, lane-local softmax) -------
// Q,K: [BH][2048][64] bf16; Vt: [BH][64][2048] bf16; ctx: [B,S,1024] bf16
// sK/sV: linear rows of 64 u16 (128B); XOR source-swizzle slot^=(row&7) at 16B
// granularity so strided ds_read_b128 is ~2-way conflict-free.
__global__ __launch_bounds__(256) void attn_fwd(const u16* __restrict__ Q,
                                                const u16* __restrict__ Kb,
                                                const u16* __restrict__ Vt,
                                                u16* __restrict__ ctx) {
  __shared__ u16 sK[64][64];
  __shared__ u16 sV[64][64];       // [d][kv]
  __shared__ u16 sP[4][16][72];    // per-wave, [q][kv]
  const int tid = threadIdx.x, lane = tid & 63, wid = tid >> 6;
  const int l16 = lane & 15, lq = lane >> 4;
  const int bh = blockIdx.y, qt = blockIdx.x;
  const size_t base = (size_t)bh * (2048 * 64);
  const int xk = l16 & 7;          // read-side XOR key (row&7 for rows ≡ l16 mod 16)

  bf16x8 qf[2];
  {
    int qrow = qt * 64 + wid * 16 + l16;
    qf[0] = *(const bf16x8*)(Q + base + (size_t)qrow * 64 + lq * 8);
    qf[1] = *(const bf16x8*)(Q + base + (size_t)qrow * 64 + 32 + lq * 8);
  }
  f32x4 o[4];
  for (int j = 0; j < 4; j++) o[j] = (f32x4){0.f, 0.f, 0.f, 0.f};
  float mrow = -3e38f, lrow = 0.f;

  // staging geometry: wave wid covers rows [wid*16, wid*16+16) of sK and sV,
  // two calls of 8 rows each; lane i -> row +i/8, 16B slot (i&7)^(row&7).
  const int srow_c = lane >> 3;                 // 0..7 within call
  const int sslot = ((lane & 7) ^ srow_c) * 8;  // swizzled source slot (u16 units)

  for (int kv0 = 0; kv0 < 2048; kv0 += 64) {
    __syncthreads();
    for (int c = 0; c < 2; c++) {
      int row = wid * 16 + c * 8 + srow_c;
      gload_lds16(Kb + base + (size_t)(kv0 + row) * 64 + sslot, &sK[wid * 16 + c * 8][0]);
      gload_lds16(Vt + base + (size_t)row * 2048 + kv0 + sslot, &sV[wid * 16 + c * 8][0]);
    }
    __syncthreads();

    // S^T = K * Q^T : sf[j][r] = S[q=l16][kv=j*16+lq*4+r]
    f32x4 sf[4];
    for (int j = 0; j < 4; j++) sf[j] = (f32x4){0.f, 0.f, 0.f, 0.f};
    for (int ks = 0; ks < 2; ks++)
      for (int j = 0; j < 4; j++) {
        bf16x8 kf = *(const bf16x8*)&sK[j * 16 + l16][((ks * 4 + lq) ^ xk) * 8];
        sf[j] = __builtin_amdgcn_mfma_f32_16x16x32_bf16(kf, qf[ks], sf[j], 0, 0, 0);
      }

    // lane-local softmax over 16 regs + 2-shfl cross-group reduce
    float pm = sf[0][0];
    for (int j = 0; j < 4; j++)
      for (int r = 0; r < 4; r++) pm = fmaxf(pm, sf[j][r]);
    pm *= 0.125f;
    pm = fmaxf(pm, __shfl_xor(pm, 16));
    pm = fmaxf(pm, __shfl_xor(pm, 32));
    float mn = fmaxf(mrow, pm);
    float osc = __expf(mrow - mn);
    mrow = mn;

    float rs = 0.f;
    for (int j = 0; j < 4; j++) {
      float p0 = __expf(sf[j][0] * 0.125f - mn);
      float p1 = __expf(sf[j][1] * 0.125f - mn);
      float p2 = __expf(sf[j][2] * 0.125f - mn);
      float p3 = __expf(sf[j][3] * 0.125f - mn);
      rs += (p0 + p1) + (p2 + p3);
      ushort4 pw;
      pw.x = f2b(p0); pw.y = f2b(p1); pw.z = f2b(p2); pw.w = f2b(p3);
      *(ushort4*)&sP[wid][l16][j * 16 + lq * 4] = pw;
    }
    rs += __shfl_xor(rs, 16);
    rs += __shfl_xor(rs, 32);
    lrow = lrow * osc + rs;

    // rescale O: need osc of q=lq*4+r (osc is indexed by q=l16)
    float oscr[4];
    for (int r = 0; r < 4; r++) oscr[r] = __shfl(osc, lq * 4 + r);
    for (int j = 0; j < 4; j++)
      for (int r = 0; r < 4; r++) o[j][r] *= oscr[r];

    // PV: O += P * V^T  (pf: A row=q=l16; vf: B col=d=l16)
    for (int ks = 0; ks < 2; ks++) {
      bf16x8 pf = *(const bf16x8*)&sP[wid][l16][ks * 32 + lq * 8];
      for (int j = 0; j < 4; j++) {
        bf16x8 vf = *(const bf16x8*)&sV[j * 16 + l16][((ks * 4 + lq) ^ xk) * 8];
        o[j] = __builtin_amdgcn_mfma_f32_16x16x32_bf16(pf, vf, o[j], 0, 0, 0);
      }
    }
  }

  float lval[4];
  for (int r = 0; r < 4; r++) lval[r] = 1.f / __shfl(lrow, lq * 4 + r);
  const int b = bh >> 4, h = bh & 15;
  for (int j = 0; j < 4; j++)
    for (int r = 0; r < 4; r++) {
      int srow = qt * 64 + wid * 16 + lq * 4 + r;
      int d = j * 16 + l16;
      ctx[((size_t)(b * 2048 + srow)) * 1024 + h * 64 + d] = f2b(o[j][r] * lval[r]);
    }
}

// ---------------- residual + LayerNorm ----------------
template <int B_BF16, int WRITE_BF16>
__global__ __launch_bounds__(256) void ln_res(const float* __restrict__ a,
                                              const void* __restrict__ bsrc,
                                              const float* __restrict__ g,
                                              const float* __restrict__ be,
                                              float* __restrict__ outf,
                                              u16* __restrict__ outb) {
  const int row = blockIdx.x, tid = threadIdx.x;
  const size_t off = (size_t)row * 1024 + tid * 4;
  float4 x = *(const float4*)(a + off);
  if constexpr (B_BF16) {
    const u16* bp = (const u16*)bsrc + off;
    x.x += b2f(bp[0]); x.y += b2f(bp[1]); x.z += b2f(bp[2]); x.w += b2f(bp[3]);
  } else {
    float4 bb = *(const float4*)((const float*)bsrc + off);
    x.x += bb.x; x.y += bb.y; x.z += bb.z; x.w += bb.w;
  }
  float s = x.x + x.y + x.z + x.w;
  float s2 = x.x * x.x + x.y * x.y + x.z * x.z + x.w * x.w;
  for (int o = 1; o < 64; o <<= 1) {
    s += __shfl_xor(s, o);
    s2 += __shfl_xor(s2, o);
  }
  __shared__ float rbuf[8];
  int lane = tid & 63, wid = tid >> 6;
  if (lane == 0) { rbuf[wid] = s; rbuf[4 + wid] = s2; }
  __syncthreads();
  s = rbuf[0] + rbuf[1] + rbuf[2] + rbuf[3];
  s2 = rbuf[4] + rbuf[5] + rbuf[6] + rbuf[7];
  float mu = s * (1.f / 1024.f);
  float var = s2 * (1.f / 1024.f) - mu * mu;
  float rstd = rsqrtf(var + 1e-5f);
  int c = tid * 4;
  float y0 = (x.x - mu) * rstd * g[c + 0] + be[c + 0];
  float y1 = (x.y - mu) * rstd * g[c + 1] + be[c + 1];
  float y2 = (x.z - mu) * rstd * g[c + 2] + be[c + 2];
  float y3 = (x.w - mu) * rstd * g[c + 3] + be[c + 3];
  float4 y; y.x = y0; y.y = y1; y.z = y2; y.w = y3;
  *(float4*)(outf + off) = y;
  if constexpr (WRITE_BF16) {
    ushort4 yb;
    yb.x = f2b(y0); yb.y = f2b(y1); yb.z = f2b(y2); yb.w = f2b(y3);
    *(ushort4*)(outb + off) = yb;
  }
}

// ---------------- launch ----------------
extern "C" void kernel_launch(void* const* d_in, const int* in_sizes, int n_in,
                              void* d_out, int out_size, void* d_ws, size_t ws_size,
                              hipStream_t stream) {
  const float* src = (const float*)d_in[0];
  const float* Wq = (const float*)d_in[1];
  const float* bq = (const float*)d_in[2];
  const float* Wk = (const float*)d_in[3];
  const float* bk = (const float*)d_in[4];
  const float* Wv = (const float*)d_in[5];
  const float* bv = (const float*)d_in[6];
  const float* Wo = (const float*)d_in[7];
  const float* bo = (const float*)d_in[8];
  const float* W1 = (const float*)d_in[9];
  const float* b1 = (const float*)d_in[10];
  const float* W2 = (const float*)d_in[11];
  const float* b2 = (const float*)d_in[12];
  const float* g1 = (const float*)d_in[13];
  const float* be1 = (const float*)d_in[14];
  const float* g2 = (const float*)d_in[15];
  const float* be2 = (const float*)d_in[16];
  float* out = (float*)d_out;
  char* ws = (char*)d_ws;
  const size_t MB = 1ull << 20;

  u16* XB   = (u16*)(ws + 0);        // 16MB, later CTX, later FF
  u16* WQT  = (u16*)(ws + 16 * MB);  // 2MB
  u16* WKT  = (u16*)(ws + 18 * MB);
  u16* WVT  = (u16*)(ws + 20 * MB);
  u16* WOT  = (u16*)(ws + 22 * MB);
  u16* W1T  = (u16*)(ws + 24 * MB);  // 8MB
  u16* W2T  = (u16*)(ws + 32 * MB);  // 8MB
  u16* Qb   = (u16*)(ws + 40 * MB);  // 16MB
  u16* Kbuf = (u16*)(ws + 56 * MB);  // 16MB
  u16* Vtmp = (u16*)(ws + 72 * MB);  // 16MB
  u16* Vt   = (u16*)(ws + 88 * MB);  // 16MB
  u16* CTX  = (u16*)(ws + 0);        // reuse XB
  float* AO = (float*)(ws + 40 * MB);   // 32MB, reuse Q/K
  float* XF = (float*)(ws + 104 * MB);  // 32MB
  u16* XBUF = (u16*)(ws + 136 * MB);    // 16MB  (peak 152MB)
  u16* H1   = (u16*)(ws + 40 * MB);     // 64MB, reuse [40,104)
  u16* FF   = (u16*)(ws + 0);           // 16MB, reuse CTX

  cvt_bf16<<<dim3(8192), dim3(256), 0, stream>>>(src, XB, 2097152);
  transpose_w<<<dim3(32, 32), dim3(256), 0, stream>>>(Wq, WQT, 1024, 1024);
  transpose_w<<<dim3(32, 32), dim3(256), 0, stream>>>(Wk, WKT, 1024, 1024);
  transpose_w<<<dim3(32, 32), dim3(256), 0, stream>>>(Wv, WVT, 1024, 1024);
  transpose_w<<<dim3(32, 32), dim3(256), 0, stream>>>(Wo, WOT, 1024, 1024);
  transpose_w<<<dim3(128, 32), dim3(256), 0, stream>>>(W1, W1T, 1024, 4096);
  transpose_w<<<dim3(32, 128), dim3(256), 0, stream>>>(W2, W2T, 4096, 1024);

  gemm_bt<3><<<dim3(64, 8), dim3(256), 0, stream>>>(XB, WQT, bq, Qb, 8192, 1024, 1024);
  gemm_bt<3><<<dim3(64, 8), dim3(256), 0, stream>>>(XB, WKT, bk, Kbuf, 8192, 1024, 1024);
  gemm_bt<3><<<dim3(64, 8), dim3(256), 0, stream>>>(XB, WVT, bv, Vtmp, 8192, 1024, 1024);
  transpose_v<<<dim3(32, 64), dim3(256), 0, stream>>>(Vtmp, Vt);
  attn_fwd<<<dim3(32, 64), dim3(256), 0, stream>>>(Qb, Kbuf, Vt, CTX);
  gemm_bt<0><<<dim3(64, 8), dim3(256), 0, stream>>>(CTX, WOT, bo, AO, 8192, 1024, 1024);
  ln_res<0, 1><<<dim3(8192), dim3(256), 0, stream>>>(src, AO, g1, be1, XF, XBUF);
  gemm_bt<2><<<dim3(64, 32), dim3(256), 0, stream>>>(XBUF, W1T, b1, H1, 8192, 4096, 1024);
  gemm_bt<1><<<dim3(64, 8), dim3(256), 0, stream>>>(H1, W2T, b2, FF, 8192, 1024, 4096);
  ln_res<1, 0><<<dim3(8192), dim3(256), 0, stream>>>(XF, FF, g2, be2, out, nullptr);
}

// Round 3
// 491.723 us; speedup vs baseline: 1.2218x; 1.0488x over previous
//
#include <hip/hip_runtime.h>

typedef __attribute__((ext_vector_type(8))) short bf16x8;
typedef __attribute__((ext_vector_type(4))) float f32x4;
typedef unsigned short u16;
typedef unsigned int u32;

__device__ __forceinline__ u16 f2b(float f) {
  u32 u = __float_as_uint(f);
  u = (u + 0x7fffu + ((u >> 16) & 1u)) >> 16;
  return (u16)u;
}
__device__ __forceinline__ float b2f(u16 b) {
  return __uint_as_float(((u32)b) << 16);
}
__device__ __forceinline__ u32 cvtpk_bf16(float lo, float hi) {
  u32 r;
  asm("v_cvt_pk_bf16_f32 %0, %1, %2" : "=v"(r) : "v"(lo), "v"(hi));
  return r;
}

__device__ __forceinline__ void gload_lds16(const u16* g, u16* l) {
  __builtin_amdgcn_global_load_lds(
      (const __attribute__((address_space(1))) void*)g,
      (__attribute__((address_space(3))) void*)l, 16, 0, 0);
}

// ---------------- convert fp32 -> bf16 (vectorized) ----------------
__global__ __launch_bounds__(256) void cvt_bf16(const float* __restrict__ in,
                                                u16* __restrict__ out, int n4) {
  int i = blockIdx.x * 256 + threadIdx.x;
  if (i >= n4) return;
  float4 v = ((const float4*)in)[i];
  ushort4 o;
  o.x = f2b(v.x); o.y = f2b(v.y); o.z = f2b(v.z); o.w = f2b(v.w);
  ((ushort4*)out)[i] = o;
}

// ------------- transpose weight [R][C] fp32 -> [C][R] bf16 -------------
__global__ __launch_bounds__(256) void transpose_w(const float* __restrict__ in,
                                                   u16* __restrict__ out,
                                                   int R, int C) {
  __shared__ float t[32][33];
  int tid = threadIdx.x, tx = tid & 31, ty = tid >> 5;
  int rb = blockIdx.y * 32, cb = blockIdx.x * 32;
  for (int i = 0; i < 4; i++)
    t[ty + i * 8][tx] = in[(size_t)(rb + ty + i * 8) * C + cb + tx];
  __syncthreads();
  for (int i = 0; i < 4; i++)
    out[(size_t)(cb + ty + i * 8) * R + rb + tx] = f2b(t[tx][ty + i * 8]);
}

// ---------------- GEMM: C[M,N] = A[M,K](bf16) * Bt[N,K]^T + bias ----------------
// m97 structure: global_load_lds(16B) into linear LDS, 2 barriers/K-step.
// MODE 0: fp32 out; 1: bf16 out; 2: bf16 relu out;
// MODE 3: bf16 out scattered to [B,H,S,64], scaled by oscale;
// MODE 5: bf16 out transposed to Vt [B*H][64][2048]
template <int MODE>
__global__ __launch_bounds__(256) void gemm_bt(const u16* __restrict__ A,
                                               const u16* __restrict__ Bt,
                                               const float* __restrict__ bias,
                                               void* __restrict__ out,
                                               int M, int N, int K, float oscale) {
  __shared__ u16 sA[128][32];
  __shared__ u16 sB[128][32];
  const int tid = threadIdx.x, lane = tid & 63, wid = tid >> 6;
  const int l16 = lane & 15, lq = lane >> 4;
  const int wr = wid >> 1, wc = wid & 1;
  const size_t abase = (size_t)blockIdx.x * 128 * K;
  const size_t bbase = (size_t)blockIdx.y * 128 * K;
  const int srow0 = wid * 32 + (lane >> 2);
  const int scol = (lane & 3) * 8;

  f32x4 acc[4][4];
  for (int i = 0; i < 4; i++)
    for (int j = 0; j < 4; j++) acc[i][j] = (f32x4){0.f, 0.f, 0.f, 0.f};

  for (int kk = 0; kk < K; kk += 32) {
    const u16* ap = A + abase + (size_t)srow0 * K + kk + scol;
    const u16* bp = Bt + bbase + (size_t)srow0 * K + kk + scol;
    __syncthreads();
    gload_lds16(ap, &sA[wid * 32][0]);
    gload_lds16(ap + (size_t)16 * K, &sA[wid * 32 + 16][0]);
    gload_lds16(bp, &sB[wid * 32][0]);
    gload_lds16(bp + (size_t)16 * K, &sB[wid * 32 + 16][0]);
    __syncthreads();
    bf16x8 af[4], bfr[4];
    for (int i = 0; i < 4; i++)
      af[i] = *(const bf16x8*)&sA[wr * 64 + i * 16 + l16][lq * 8];
    for (int j = 0; j < 4; j++)
      bfr[j] = *(const bf16x8*)&sB[wc * 64 + j * 16 + l16][lq * 8];
    for (int i = 0; i < 4; i++)
      for (int j = 0; j < 4; j++)
        acc[i][j] = __builtin_amdgcn_mfma_f32_16x16x32_bf16(af[i], bfr[j],
                                                            acc[i][j], 0, 0, 0);
  }

  for (int i = 0; i < 4; i++) {
    int gm0 = blockIdx.x * 128 + wr * 64 + i * 16 + lq * 4;
    for (int j = 0; j < 4; j++) {
      int gn = blockIdx.y * 128 + wc * 64 + j * 16 + l16;
      float bv = bias[gn];
      if constexpr (MODE == 5) {
        // transposed write: Vt[((b*16+h)*64+d)][s], 4 consecutive s per lane
        int b = gm0 >> 11, s = gm0 & 2047, h = gn >> 6, d = gn & 63;
        ushort4 w;
        w.x = f2b(acc[i][j][0] + bv);
        w.y = f2b(acc[i][j][1] + bv);
        w.z = f2b(acc[i][j][2] + bv);
        w.w = f2b(acc[i][j][3] + bv);
        *(ushort4*)((u16*)out + ((size_t)((b * 16 + h) * 64 + d)) * 2048 + s) = w;
      } else {
        for (int r = 0; r < 4; r++) {
          float v = acc[i][j][r] + bv;
          int gm = gm0 + r;
          if constexpr (MODE == 0) {
            ((float*)out)[(size_t)gm * N + gn] = v;
          } else if constexpr (MODE == 1) {
            ((u16*)out)[(size_t)gm * N + gn] = f2b(v);
          } else if constexpr (MODE == 2) {
            ((u16*)out)[(size_t)gm * N + gn] = f2b(v > 0.f ? v : 0.f);
          } else {
            int b = gm >> 11, s = gm & 2047, h = gn >> 6, d = gn & 63;
            ((u16*)out)[((size_t)(b * 16 + h) * 2048 + s) * 64 + d] = f2b(v * oscale);
          }
        }
      }
    }
  }
}

// ---------------- flash attention fwd (swapped QK^T, lane-local softmax) -------
// Q (pre-scaled by 0.125*log2e), K: [BH][2048][64] bf16; Vt: [BH][64][2048] bf16
// scores are in log2 domain -> v_exp_f32 directly; T13 defer-max skips rescale.
__global__ __launch_bounds__(256) void attn_fwd(const u16* __restrict__ Q,
                                                const u16* __restrict__ Kb,
                                                const u16* __restrict__ Vt,
                                                u16* __restrict__ ctx) {
  __shared__ u16 sK[64][64];
  __shared__ u16 sV[64][64];       // [d][kv]
  __shared__ u16 sP[4][16][72];    // per-wave, [q][kv]
  const int tid = threadIdx.x, lane = tid & 63, wid = tid >> 6;
  const int l16 = lane & 15, lq = lane >> 4;
  const int bh = blockIdx.y, qt = blockIdx.x;
  const size_t base = (size_t)bh * (2048 * 64);
  const int xk = l16 & 7;

  bf16x8 qf[2];
  {
    int qrow = qt * 64 + wid * 16 + l16;
    qf[0] = *(const bf16x8*)(Q + base + (size_t)qrow * 64 + lq * 8);
    qf[1] = *(const bf16x8*)(Q + base + (size_t)qrow * 64 + 32 + lq * 8);
  }
  f32x4 o[4];
  for (int j = 0; j < 4; j++) o[j] = (f32x4){0.f, 0.f, 0.f, 0.f};
  float mrow = -3e38f, lrow = 0.f;

  const int srow_c = lane >> 3;
  const int sslot = ((lane & 7) ^ srow_c) * 8;

  for (int kv0 = 0; kv0 < 2048; kv0 += 64) {
    __syncthreads();
    for (int c = 0; c < 2; c++) {
      int row = wid * 16 + c * 8 + srow_c;
      gload_lds16(Kb + base + (size_t)(kv0 + row) * 64 + sslot, &sK[wid * 16 + c * 8][0]);
      gload_lds16(Vt + base + (size_t)row * 2048 + kv0 + sslot, &sV[wid * 16 + c * 8][0]);
    }
    __syncthreads();

    // S^T = K * Q^T (log2 domain): sf[j][r] = S[q=l16][kv=j*16+lq*4+r]
    f32x4 sf[4];
    for (int j = 0; j < 4; j++) sf[j] = (f32x4){0.f, 0.f, 0.f, 0.f};
    for (int ks = 0; ks < 2; ks++)
      for (int j = 0; j < 4; j++) {
        bf16x8 kf = *(const bf16x8*)&sK[j * 16 + l16][((ks * 4 + lq) ^ xk) * 8];
        sf[j] = __builtin_amdgcn_mfma_f32_16x16x32_bf16(kf, qf[ks], sf[j], 0, 0, 0);
      }

    // row max (16 regs + 2 shfl)
    float pm = fmaxf(fmaxf(fmaxf(sf[0][0], sf[0][1]), fmaxf(sf[0][2], sf[0][3])),
                     fmaxf(fmaxf(sf[1][0], sf[1][1]), fmaxf(sf[1][2], sf[1][3])));
    pm = fmaxf(pm,
               fmaxf(fmaxf(fmaxf(sf[2][0], sf[2][1]), fmaxf(sf[2][2], sf[2][3])),
                     fmaxf(fmaxf(sf[3][0], sf[3][1]), fmaxf(sf[3][2], sf[3][3]))));
    pm = fmaxf(pm, __shfl_xor(pm, 16));
    pm = fmaxf(pm, __shfl_xor(pm, 32));

    // T13 defer-max: only rescale when the running max moved by >8 (log2 units)
    if (!__all(pm - mrow <= 8.f)) {
      float mn = fmaxf(mrow, pm);
      float osc = __builtin_amdgcn_exp2f(mrow - mn);
      mrow = mn;
      lrow *= osc;
      float oscr[4];
      for (int r = 0; r < 4; r++) oscr[r] = __shfl(osc, lq * 4 + r);
      for (int j = 0; j < 4; j++)
        for (int r = 0; r < 4; r++) o[j][r] *= oscr[r];
    }

    float rs = 0.f;
    for (int j = 0; j < 4; j++) {
      float p0 = __builtin_amdgcn_exp2f(sf[j][0] - mrow);
      float p1 = __builtin_amdgcn_exp2f(sf[j][1] - mrow);
      float p2 = __builtin_amdgcn_exp2f(sf[j][2] - mrow);
      float p3 = __builtin_amdgcn_exp2f(sf[j][3] - mrow);
      rs += (p0 + p1) + (p2 + p3);
      uint2 w;
      w.x = cvtpk_bf16(p0, p1);
      w.y = cvtpk_bf16(p2, p3);
      *(uint2*)&sP[wid][l16][j * 16 + lq * 4] = w;
    }
    rs += __shfl_xor(rs, 16);
    rs += __shfl_xor(rs, 32);
    lrow += rs;

    // PV: O += P * V^T
    for (int ks = 0; ks < 2; ks++) {
      bf16x8 pf = *(const bf16x8*)&sP[wid][l16][ks * 32 + lq * 8];
      for (int j = 0; j < 4; j++) {
        bf16x8 vf = *(const bf16x8*)&sV[j * 16 + l16][((ks * 4 + lq) ^ xk) * 8];
        o[j] = __builtin_amdgcn_mfma_f32_16x16x32_bf16(pf, vf, o[j], 0, 0, 0);
      }
    }
  }

  float lval[4];
  for (int r = 0; r < 4; r++) lval[r] = 1.f / __shfl(lrow, lq * 4 + r);
  const int b = bh >> 4, h = bh & 15;
  for (int j = 0; j < 4; j++)
    for (int r = 0; r < 4; r++) {
      int srow = qt * 64 + wid * 16 + lq * 4 + r;
      int d = j * 16 + l16;
      ctx[((size_t)(b * 2048 + srow)) * 1024 + h * 64 + d] = f2b(o[j][r] * lval[r]);
    }
}

// ---------------- residual + LayerNorm ----------------
template <int B_BF16, int WRITE_BF16>
__global__ __launch_bounds__(256) void ln_res(const float* __restrict__ a,
                                              const void* __restrict__ bsrc,
                                              const float* __restrict__ g,
                                              const float* __restrict__ be,
                                              float* __restrict__ outf,
                                              u16* __restrict__ outb) {
  const int row = blockIdx.x, tid = threadIdx.x;
  const size_t off = (size_t)row * 1024 + tid * 4;
  float4 x = *(const float4*)(a + off);
  if constexpr (B_BF16) {
    const u16* bp = (const u16*)bsrc + off;
    x.x += b2f(bp[0]); x.y += b2f(bp[1]); x.z += b2f(bp[2]); x.w += b2f(bp[3]);
  } else {
    float4 bb = *(const float4*)((const float*)bsrc + off);
    x.x += bb.x; x.y += bb.y; x.z += bb.z; x.w += bb.w;
  }
  float s = x.x + x.y + x.z + x.w;
  float s2 = x.x * x.x + x.y * x.y + x.z * x.z + x.w * x.w;
  for (int o = 1; o < 64; o <<= 1) {
    s += __shfl_xor(s, o);
    s2 += __shfl_xor(s2, o);
  }
  __shared__ float rbuf[8];
  int lane = tid & 63, wid = tid >> 6;
  if (lane == 0) { rbuf[wid] = s; rbuf[4 + wid] = s2; }
  __syncthreads();
  s = rbuf[0] + rbuf[1] + rbuf[2] + rbuf[3];
  s2 = rbuf[4] + rbuf[5] + rbuf[6] + rbuf[7];
  float mu = s * (1.f / 1024.f);
  float var = s2 * (1.f / 1024.f) - mu * mu;
  float rstd = rsqrtf(var + 1e-5f);
  int c = tid * 4;
  float y0 = (x.x - mu) * rstd * g[c + 0] + be[c + 0];
  float y1 = (x.y - mu) * rstd * g[c + 1] + be[c + 1];
  float y2 = (x.z - mu) * rstd * g[c + 2] + be[c + 2];
  float y3 = (x.w - mu) * rstd * g[c + 3] + be[c + 3];
  float4 y; y.x = y0; y.y = y1; y.z = y2; y.w = y3;
  *(float4*)(outf + off) = y;
  if constexpr (WRITE_BF16) {
    ushort4 yb;
    yb.x = f2b(y0); yb.y = f2b(y1); yb.z = f2b(y2); yb.w = f2b(y3);
    *(ushort4*)(outb + off) = yb;
  }
}

// ---------------- launch ----------------
extern "C" void kernel_launch(void* const* d_in, const int* in_sizes, int n_in,
                              void* d_out, int out_size, void* d_ws, size_t ws_size,
                              hipStream_t stream) {
  const float* src = (const float*)d_in[0];
  const float* Wq = (const float*)d_in[1];
  const float* bq = (const float*)d_in[2];
  const float* Wk = (const float*)d_in[3];
  const float* bk = (const float*)d_in[4];
  const float* Wv = (const float*)d_in[5];
  const float* bv = (const float*)d_in[6];
  const float* Wo = (const float*)d_in[7];
  const float* bo = (const float*)d_in[8];
  const float* W1 = (const float*)d_in[9];
  const float* b1 = (const float*)d_in[10];
  const float* W2 = (const float*)d_in[11];
  const float* b2 = (const float*)d_in[12];
  const float* g1 = (const float*)d_in[13];
  const float* be1 = (const float*)d_in[14];
  const float* g2 = (const float*)d_in[15];
  const float* be2 = (const float*)d_in[16];
  float* out = (float*)d_out;
  char* ws = (char*)d_ws;
  const size_t MB = 1ull << 20;

  u16* XB   = (u16*)(ws + 0);        // 16MB, later CTX, later FF
  u16* WQT  = (u16*)(ws + 16 * MB);  // 2MB
  u16* WKT  = (u16*)(ws + 18 * MB);
  u16* WVT  = (u16*)(ws + 20 * MB);
  u16* WOT  = (u16*)(ws + 22 * MB);
  u16* W1T  = (u16*)(ws + 24 * MB);  // 8MB
  u16* W2T  = (u16*)(ws + 32 * MB);  // 8MB
  u16* Qb   = (u16*)(ws + 40 * MB);  // 16MB
  u16* Kbuf = (u16*)(ws + 56 * MB);  // 16MB
  u16* Vt   = (u16*)(ws + 88 * MB);  // 16MB
  u16* CTX  = (u16*)(ws + 0);        // reuse XB
  float* AO = (float*)(ws + 40 * MB);   // 32MB, reuse Q/K
  float* XF = (float*)(ws + 104 * MB);  // 32MB
  u16* XBUF = (u16*)(ws + 136 * MB);    // 16MB  (peak 152MB)
  u16* H1   = (u16*)(ws + 40 * MB);     // 64MB, reuse [40,104)
  u16* FF   = (u16*)(ws + 0);           // 16MB, reuse CTX

  const float QSCALE = 0.125f * 1.44269504088896340736f;  // 1/sqrt(64) * log2(e)

  cvt_bf16<<<dim3(8192), dim3(256), 0, stream>>>(src, XB, 2097152);
  transpose_w<<<dim3(32, 32), dim3(256), 0, stream>>>(Wq, WQT, 1024, 1024);
  transpose_w<<<dim3(32, 32), dim3(256), 0, stream>>>(Wk, WKT, 1024, 1024);
  transpose_w<<<dim3(32, 32), dim3(256), 0, stream>>>(Wv, WVT, 1024, 1024);
  transpose_w<<<dim3(32, 32), dim3(256), 0, stream>>>(Wo, WOT, 1024, 1024);
  transpose_w<<<dim3(128, 32), dim3(256), 0, stream>>>(W1, W1T, 1024, 4096);
  transpose_w<<<dim3(32, 128), dim3(256), 0, stream>>>(W2, W2T, 4096, 1024);

  gemm_bt<3><<<dim3(64, 8), dim3(256), 0, stream>>>(XB, WQT, bq, Qb, 8192, 1024, 1024, QSCALE);
  gemm_bt<3><<<dim3(64, 8), dim3(256), 0, stream>>>(XB, WKT, bk, Kbuf, 8192, 1024, 1024, 1.0f);
  gemm_bt<5><<<dim3(64, 8), dim3(256), 0, stream>>>(XB, WVT, bv, Vt, 8192, 1024, 1024, 1.0f);
  attn_fwd<<<dim3(32, 64), dim3(256), 0, stream>>>(Qb, Kbuf, Vt, CTX);
  gemm_bt<0><<<dim3(64, 8), dim3(256), 0, stream>>>(CTX, WOT, bo, AO, 8192, 1024, 1024, 1.0f);
  ln_res<0, 1><<<dim3(8192), dim3(256), 0, stream>>>(src, AO, g1, be1, XF, XBUF);
  gemm_bt<2><<<dim3(64, 32), dim3(256), 0, stream>>>(XBUF, W1T, b1, H1, 8192, 4096, 1024, 1.0f);
  gemm_bt<1><<<dim3(64, 8), dim3(256), 0, stream>>>(H1, W2T, b2, FF, 8192, 1024, 4096, 1.0f);
  ln_res<1, 0><<<dim3(8192), dim3(256), 0, stream>>>(XF, FF, g2, be2, out, nullptr);
}